// Round 1
// baseline (20.684 us; speedup 1.0000x reference)
//
#include <hip/hip_runtime.h>

#define T_LEN 16384
#define B_N   128
#define P_N   32
#define S_N   31
#define M_SH  15
#define NCHUNK 16
#define TCHUNK (T_LEN / NCHUNK)      // 1024
#define BLOCK  256
#define NBLOCKS (B_N * NCHUNK)       // 2048

// Kernel 0: per-batch softmax weights. One block, thread b handles row b.
__global__ void talos_weights(const float* __restrict__ theta,
                              const int* __restrict__ pidx,
                              float* __restrict__ w_out) {
    int b = threadIdx.x;
    if (b >= B_N) return;
    const float* th = theta + pidx[b] * S_N;
    float v[S_N];
    float m = -1e30f;
#pragma unroll
    for (int s = 0; s < S_N; ++s) { v[s] = th[s]; m = fmaxf(m, v[s]); }
    float sum = 0.f;
#pragma unroll
    for (int s = 0; s < S_N; ++s) { v[s] = __expf(v[s] - m); sum += v[s]; }
    float inv = 1.f / sum;
#pragma unroll
    for (int s = 0; s < S_N; ++s) w_out[b * S_N + s] = v[s] * inv;
}

// Kernel 1: per-(b, t-chunk) weighted shifted-MSE partial sums.
__global__ __launch_bounds__(BLOCK) void talos_partial(
    const float* __restrict__ y_pred,
    const float* __restrict__ y_true,
    const float* __restrict__ w_all,
    float* __restrict__ partial) {
    __shared__ float tile[TCHUNK + 2 * M_SH];
    __shared__ float wsh[S_N];
    __shared__ float red[BLOCK / 64];

    const int bid   = blockIdx.x;
    const int b     = bid / NCHUNK;
    const int chunk = bid % NCHUNK;
    const int t0    = chunk * TCHUNK;
    const int tid   = threadIdx.x;

    if (tid < S_N) wsh[tid] = w_all[b * S_N + tid];

    // Stage y_true chunk with +/-15 halo; zero-pad out of range (matches jnp.pad).
    for (int i = tid; i < TCHUNK + 2 * M_SH; i += BLOCK) {
        int g = t0 - M_SH + i;
        tile[i] = (g >= 0 && g < T_LEN) ? y_true[b * T_LEN + g] : 0.f;
    }
    __syncthreads();

    float w[S_N];
#pragma unroll
    for (int s = 0; s < S_N; ++s) w[s] = wsh[s];

    float acc = 0.f;
#pragma unroll
    for (int k = 0; k < TCHUNK / BLOCK; ++k) {
        const int lt = tid + k * BLOCK;          // strided: lanes hit distinct banks
        const float yp = y_pred[b * T_LEN + t0 + lt];
#pragma unroll
        for (int s = 0; s < S_N; ++s) {
            float d = yp - tile[lt + s];
            acc = fmaf(w[s] * d, d, acc);
        }
    }

    // wave (64-lane) shuffle reduce, then cross-wave via LDS
#pragma unroll
    for (int off = 32; off > 0; off >>= 1) acc += __shfl_down(acc, off, 64);
    const int lane = tid & 63, wv = tid >> 6;
    if (lane == 0) red[wv] = acc;
    __syncthreads();
    if (tid == 0) {
        float s = 0.f;
#pragma unroll
        for (int i = 0; i < BLOCK / 64; ++i) s += red[i];
        partial[bid] = s;
    }
}

// Kernel 2: deterministic final reduction of 2048 partials -> scalar.
__global__ __launch_bounds__(256) void talos_final(
    const float* __restrict__ partial, float* __restrict__ out) {
    __shared__ double red[4];
    const int tid = threadIdx.x;
    double acc = 0.0;
    for (int i = tid; i < NBLOCKS; i += 256) acc += (double)partial[i];
#pragma unroll
    for (int off = 32; off > 0; off >>= 1) acc += __shfl_down(acc, off, 64);
    const int lane = tid & 63, wv = tid >> 6;
    if (lane == 0) red[wv] = acc;
    __syncthreads();
    if (tid == 0) {
        double tot = red[0] + red[1] + red[2] + red[3];
        out[0] = (float)(tot / ((double)T_LEN * (double)B_N));
    }
}

extern "C" void kernel_launch(void* const* d_in, const int* in_sizes, int n_in,
                              void* d_out, int out_size, void* d_ws, size_t ws_size,
                              hipStream_t stream) {
    const float* y_pred = (const float*)d_in[0];
    const float* y_true = (const float*)d_in[1];
    const float* theta  = (const float*)d_in[2];
    const int*   pidx   = (const int*)d_in[3];
    float* out = (float*)d_out;

    float* w_all   = (float*)d_ws;                    // B_N * S_N floats
    float* partial = (float*)d_ws + 4096;             // NBLOCKS floats (aligned past weights)

    talos_weights<<<1, 128, 0, stream>>>(theta, pidx, w_all);
    talos_partial<<<NBLOCKS, BLOCK, 0, stream>>>(y_pred, y_true, w_all, partial);
    talos_final<<<1, 256, 0, stream>>>(partial, out);
}

// Round 2
// 12.777 us; speedup vs baseline: 1.6188x; 1.6188x over previous
//
#include <hip/hip_runtime.h>
#include <math.h>

#define T_LEN 16384
#define B_N   128
#define S_N   31
#define M_SH  15
#define NCHUNK 8
#define TCHUNK (T_LEN / NCHUNK)   // 2048
#define BLOCK  256
#define VT     8
#define NBLOCKS (B_N * NCHUNK)    // 1024
#define HALO   16
#define TILE_F4 ((TCHUNK + 2 * HALO) / 4)   // 520

// XOR swizzle at float4 granularity: spreads the 32B-strided window reads
// across banks (worst case 2 lanes/bank = free). Bijective within 128B groups.
__device__ __forceinline__ int swz(int f4) { return f4 ^ ((f4 >> 3) & 7); }

__global__ __launch_bounds__(BLOCK) void talos_main(
    const float* __restrict__ y_pred,
    const float* __restrict__ y_true,
    const float* __restrict__ theta,
    const int* __restrict__ pidx,
    float* __restrict__ accp,
    float* __restrict__ sqp) {

  __shared__ float tile[TILE_F4 * 4];          // 8320 B, swizzled
  __shared__ float wsh[S_N];
  __shared__ float redL[BLOCK / 64], redS[BLOCK / 64];

  const int bid   = blockIdx.x;
  const int b     = bid / NCHUNK;
  const int chunk = bid % NCHUNK;
  const int t0    = chunk * TCHUNK;
  const int tid   = threadIdx.x;
  const float* yt_b = y_true + b * T_LEN;
  const float* yp_b = y_pred + b * T_LEN;

  // ---- stage y_true chunk + halo into swizzled LDS (float4, zero-padded) ----
  for (int f = tid; f < TILE_F4; f += BLOCK) {
    int g = t0 - HALO + f * 4;                 // 16B-aligned global float index
    float4 v;
    if (g >= 0 && g + 3 < T_LEN) {
      v = *(const float4*)(yt_b + g);
    } else {
      v.x = (g + 0 >= 0 && g + 0 < T_LEN) ? yt_b[g + 0] : 0.f;
      v.y = (g + 1 >= 0 && g + 1 < T_LEN) ? yt_b[g + 1] : 0.f;
      v.z = (g + 2 >= 0 && g + 2 < T_LEN) ? yt_b[g + 2] : 0.f;
      v.w = (g + 3 >= 0 && g + 3 < T_LEN) ? yt_b[g + 3] : 0.f;
    }
    *(float4*)&tile[swz(f) * 4] = v;
  }

  // ---- softmax weights for this b (wave 0, lanes 0..31) ----
  if (tid < 32) {
    float v = (tid < S_N) ? theta[pidx[b] * S_N + tid] : -1e30f;
    float m = v;
#pragma unroll
    for (int off = 16; off; off >>= 1) m = fmaxf(m, __shfl_xor(m, off, 32));
    float e = (tid < S_N) ? __expf(v - m) : 0.f;
    float s = e;
#pragma unroll
    for (int off = 16; off; off >>= 1) s += __shfl_xor(s, off, 32);
    if (tid < S_N) wsh[tid] = e / s;
  }
  __syncthreads();

  // ---- register-blocked weighted 31-tap convolution over VT=8 elements ----
  const int lt0 = tid * VT;                    // element offset in chunk
  float yp[VT];
  *(float4*)&yp[0] = *(const float4*)(yp_b + t0 + lt0);
  *(float4*)&yp[4] = *(const float4*)(yp_b + t0 + lt0 + 4);

  float win[VT + 2 * HALO];                    // 40 floats: yt[t0+lt0-16 .. +23]
#pragma unroll
  for (int q = 0; q < (VT + 2 * HALO) / 4; ++q) {
    int f4 = (lt0 >> 2) + q;                   // 2*tid + q
    *(float4*)&win[q * 4] = *(const float4*)&tile[swz(f4) * 4];
  }

  float w[S_N];
#pragma unroll
  for (int s = 0; s < S_N; ++s) w[s] = wsh[s];

  float lin[VT];
#pragma unroll
  for (int j = 0; j < VT; ++j) lin[j] = 0.f;
#pragma unroll
  for (int s = 0; s < S_N; ++s) {
#pragma unroll
    for (int j = 0; j < VT; ++j)
      lin[j] = fmaf(w[s], win[j + s + 1], lin[j]);   // yt[t+k], k=s-15
  }

  float accL = 0.f, accS = 0.f;
#pragma unroll
  for (int j = 0; j < VT; ++j) {
    accL = fmaf(yp[j], fmaf(-2.f, lin[j], yp[j]), accL);  // yp^2 - 2*yp*lin
    float a = win[HALO + j];                              // own yt value
    accS = fmaf(a, a, accS);                              // sum yt^2 (chunk)
  }

  // ---- block reduce (2 scalars) ----
#pragma unroll
  for (int off = 32; off; off >>= 1) {
    accL += __shfl_down(accL, off, 64);
    accS += __shfl_down(accS, off, 64);
  }
  const int lane = tid & 63, wv = tid >> 6;
  if (lane == 0) { redL[wv] = accL; redS[wv] = accS; }
  __syncthreads();
  if (tid == 0) {
    float sL = 0.f, sS = 0.f;
#pragma unroll
    for (int i = 0; i < BLOCK / 64; ++i) { sL += redL[i]; sS += redS[i]; }
    accp[bid] = sL;
    sqp[bid]  = sS;
  }
}

// Final: per-b combine (weights + sq-term with edge corrections), reduce to scalar.
__global__ __launch_bounds__(128) void talos_final(
    const float* __restrict__ y_true,
    const float* __restrict__ theta,
    const int* __restrict__ pidx,
    const float* __restrict__ accp,
    const float* __restrict__ sqp,
    float* __restrict__ out) {
  __shared__ double red[2];
  const int b = threadIdx.x;                   // 0..127

  double A = 0.0, S = 0.0;
  for (int c = 0; c < NCHUNK; ++c) {
    A += (double)accp[b * NCHUNK + c];
    S += (double)sqp[b * NCHUNK + c];
  }

  const float* th = theta + pidx[b] * S_N;
  float v[S_N];
  float m = -1e30f;
#pragma unroll
  for (int s = 0; s < S_N; ++s) { v[s] = th[s]; m = fmaxf(m, v[s]); }
  float sum = 0.f;
#pragma unroll
  for (int s = 0; s < S_N; ++s) { v[s] = __expf(v[s] - m); sum += v[s]; }
  const float inv = 1.f / sum;

  // prefix/suffix sums of yt^2 at the row edges (for zero-pad correction)
  const float* yt = y_true + b * T_LEN;
  float pf[M_SH + 1], sf[M_SH + 1];
  pf[0] = 0.f; sf[0] = 0.f;
  for (int i = 1; i <= M_SH; ++i) {
    float a = yt[i - 1];        pf[i] = pf[i - 1] + a * a;
    float z = yt[T_LEN - i];    sf[i] = sf[i - 1] + z * z;
  }

  double sq = 0.0;
  for (int s = 0; s < S_N; ++s) {
    int k = s - M_SH;
    float edge = (k >= 0) ? pf[k] : sf[-k];
    sq += (double)(v[s] * inv) * (S - (double)edge);
  }

  double loss = A + sq;
#pragma unroll
  for (int off = 32; off; off >>= 1) loss += __shfl_down(loss, off, 64);
  if ((b & 63) == 0) red[b >> 6] = loss;
  __syncthreads();
  if (b == 0) out[0] = (float)((red[0] + red[1]) / ((double)T_LEN * (double)B_N));
}

extern "C" void kernel_launch(void* const* d_in, const int* in_sizes, int n_in,
                              void* d_out, int out_size, void* d_ws, size_t ws_size,
                              hipStream_t stream) {
  const float* y_pred = (const float*)d_in[0];
  const float* y_true = (const float*)d_in[1];
  const float* theta  = (const float*)d_in[2];
  const int*   pidx   = (const int*)d_in[3];
  float* out = (float*)d_out;

  float* accp = (float*)d_ws;            // NBLOCKS floats
  float* sqp  = accp + NBLOCKS;          // NBLOCKS floats

  talos_main<<<NBLOCKS, BLOCK, 0, stream>>>(y_pred, y_true, theta, pidx, accp, sqp);
  talos_final<<<1, 128, 0, stream>>>(y_true, theta, pidx, accp, sqp, out);
}